// Round 1
// baseline (51.940 us; speedup 1.0000x reference)
//
#include <hip/hip_runtime.h>

// Sobel-like 4-kernel depthwise edge detector + sigmoid>0.5 threshold.
// Output[p] = (|e0|+|e1|+|e2|+|e3| > 0) ? 1.0f : 0.0f, with zero padding.
//
// x: (32,3,512,512) f32 -> treated as 96 independent 512x512 images.
// Each thread computes 4 consecutive pixels in a row (float4 in/out).

#define IMG_H 512
#define IMG_W 512

__global__ __launch_bounds__(256) void sobel_thresh_kernel(
    const float* __restrict__ x, float* __restrict__ out, int n4) {
    int t = blockIdx.x * blockDim.x + threadIdx.x;
    if (t >= n4) return;

    // 512*512/4 = 65536 float4's per image; 128 float4's per row.
    int img = t >> 16;
    int rem = t & 65535;
    int h   = rem >> 7;
    int w0  = (rem & 127) << 2;

    const float* base = x + (size_t)img * (IMG_H * IMG_W);

    float rt[6], rm[6], rb[6];

    // center row (always in-bounds)
    {
        const float* r = base + h * IMG_W;
        float4 v = *reinterpret_cast<const float4*>(r + w0);
        rm[1] = v.x; rm[2] = v.y; rm[3] = v.z; rm[4] = v.w;
        rm[0] = (w0 > 0)           ? r[w0 - 1] : 0.0f;
        rm[5] = (w0 + 4 < IMG_W)   ? r[w0 + 4] : 0.0f;
    }
    // row above
    if (h > 0) {
        const float* r = base + (h - 1) * IMG_W;
        float4 v = *reinterpret_cast<const float4*>(r + w0);
        rt[1] = v.x; rt[2] = v.y; rt[3] = v.z; rt[4] = v.w;
        rt[0] = (w0 > 0)           ? r[w0 - 1] : 0.0f;
        rt[5] = (w0 + 4 < IMG_W)   ? r[w0 + 4] : 0.0f;
    } else {
#pragma unroll
        for (int i = 0; i < 6; ++i) rt[i] = 0.0f;
    }
    // row below
    if (h + 1 < IMG_H) {
        const float* r = base + (h + 1) * IMG_W;
        float4 v = *reinterpret_cast<const float4*>(r + w0);
        rb[1] = v.x; rb[2] = v.y; rb[3] = v.z; rb[4] = v.w;
        rb[0] = (w0 > 0)           ? r[w0 - 1] : 0.0f;
        rb[5] = (w0 + 4 < IMG_W)   ? r[w0 + 4] : 0.0f;
    } else {
#pragma unroll
        for (int i = 0; i < 6; ++i) rb[i] = 0.0f;
    }

    float res[4];
#pragma unroll
    for (int j = 0; j < 4; ++j) {
        float t0 = rt[j], t1 = rt[j + 1], t2 = rt[j + 2];
        float m0 = rm[j],                 m2 = rm[j + 2];
        float b0 = rb[j], b1 = rb[j + 1], b2 = rb[j + 2];
        // k0 = [[-1,0,1],[-2,0,2],[-1,0,1]]
        float e0 = (t2 - t0) + 2.0f * (m2 - m0) + (b2 - b0);
        // k1 = [[1,2,1],[0,0,0],[-1,-2,-1]]
        float e1 = (t0 + 2.0f * t1 + t2) - (b0 + 2.0f * b1 + b2);
        // k2 = [[2,1,0],[1,0,-1],[0,-1,-2]]
        float e2 = 2.0f * t0 + t1 + m0 - m2 - b1 - 2.0f * b2;
        // k3 = [[0,-1,-2],[1,0,-1],[2,1,0]]
        float e3 = -t1 - 2.0f * t2 + m0 - m2 + 2.0f * b0 + b1;
        float s = fabsf(e0) + fabsf(e1) + fabsf(e2) + fabsf(e3);
        res[j] = (s > 0.0f) ? 1.0f : 0.0f;
    }

    float4 o;
    o.x = res[0]; o.y = res[1]; o.z = res[2]; o.w = res[3];
    *reinterpret_cast<float4*>(out + (size_t)t * 4) = o;
}

extern "C" void kernel_launch(void* const* d_in, const int* in_sizes, int n_in,
                              void* d_out, int out_size, void* d_ws, size_t ws_size,
                              hipStream_t stream) {
    const float* x = (const float*)d_in[0];
    float* out = (float*)d_out;
    int n4 = out_size / 4;  // 6,291,456 float4 outputs
    int block = 256;
    int grid = (n4 + block - 1) / block;  // 24576 blocks
    sobel_thresh_kernel<<<grid, block, 0, stream>>>(x, out, n4);
}

// Round 3
// 38.539 us; speedup vs baseline: 1.3477x; 1.3477x over previous
//
#include <hip/hip_runtime.h>

// Sobel-like 4-kernel depthwise edge detector + sigmoid>0.5 threshold.
// Output[p] = (|e0|+|e1|+|e2|+|e3| > 0) ? 1.0f : 0.0f, with zero padding.
//
// x: (32,3,512,512) f32 -> 96 independent 512x512 images.
// Each thread computes a 4-row x 4-col tile: 6 input rows loaded once,
// amortized across 4 output rows (row-reuse in registers, not via L2).

#define IMG_H 512
#define IMG_W 512

typedef float f32x4 __attribute__((ext_vector_type(4)));

__global__ __launch_bounds__(256) void sobel_thresh_kernel(
    const float* __restrict__ x, float* __restrict__ out) {
    int t = blockIdx.x * blockDim.x + threadIdx.x;
    // layout: img (96) x hgroup (128) x wblock (128); consecutive threads
    // = consecutive wblocks -> coalesced float4 rows per wave.
    int wb  = t & 127;
    int hg  = (t >> 7) & 127;
    int img = t >> 14;
    int w0  = wb << 2;
    int h0  = hg << 2;

    const float* base = x + (size_t)img * (IMG_H * IMG_W);

    float ra[6][6];
#pragma unroll
    for (int r = 0; r < 6; ++r) {
        int h = h0 - 1 + r;
        if (h >= 0 && h < IMG_H) {
            const float* rp = base + h * IMG_W;
            f32x4 v = *reinterpret_cast<const f32x4*>(rp + w0);
            ra[r][1] = v.x; ra[r][2] = v.y; ra[r][3] = v.z; ra[r][4] = v.w;
            ra[r][0] = (w0 > 0)         ? rp[w0 - 1] : 0.0f;
            ra[r][5] = (w0 + 4 < IMG_W) ? rp[w0 + 4] : 0.0f;
        } else {
#pragma unroll
            for (int i = 0; i < 6; ++i) ra[r][i] = 0.0f;
        }
    }

    float* obase = out + (size_t)img * (IMG_H * IMG_W) + (size_t)h0 * IMG_W + w0;
#pragma unroll
    for (int i = 0; i < 4; ++i) {
        float res[4];
#pragma unroll
        for (int j = 0; j < 4; ++j) {
            float t0 = ra[i][j],     t1 = ra[i][j + 1],     t2 = ra[i][j + 2];
            float m0 = ra[i + 1][j],                        m2 = ra[i + 1][j + 2];
            float b0 = ra[i + 2][j], b1 = ra[i + 2][j + 1], b2 = ra[i + 2][j + 2];
            // k0 = [[-1,0,1],[-2,0,2],[-1,0,1]]
            float e0 = (t2 - t0) + 2.0f * (m2 - m0) + (b2 - b0);
            // k1 = [[1,2,1],[0,0,0],[-1,-2,-1]]
            float e1 = (t0 + 2.0f * t1 + t2) - (b0 + 2.0f * b1 + b2);
            // k2 = [[2,1,0],[1,0,-1],[0,-1,-2]]
            float e2 = 2.0f * t0 + t1 + m0 - m2 - b1 - 2.0f * b2;
            // k3 = [[0,-1,-2],[1,0,-1],[2,1,0]]
            float e3 = -t1 - 2.0f * t2 + m0 - m2 + 2.0f * b0 + b1;
            float s = fabsf(e0) + fabsf(e1) + fabsf(e2) + fabsf(e3);
            res[j] = (s > 0.0f) ? 1.0f : 0.0f;
        }
        f32x4 o;
        o.x = res[0]; o.y = res[1]; o.z = res[2]; o.w = res[3];
        __builtin_nontemporal_store(o, reinterpret_cast<f32x4*>(obase + i * IMG_W));
    }
}

extern "C" void kernel_launch(void* const* d_in, const int* in_sizes, int n_in,
                              void* d_out, int out_size, void* d_ws, size_t ws_size,
                              hipStream_t stream) {
    const float* x = (const float*)d_in[0];
    float* out = (float*)d_out;
    // 96 imgs * 128 hgroups * 128 wblocks = 1,572,864 threads
    int total = 96 * 128 * 128;
    int block = 256;
    int grid = total / block;  // 6144 blocks
    sobel_thresh_kernel<<<grid, block, 0, stream>>>(x, out);
}